// Round 1
// baseline (568.937 us; speedup 1.0000x reference)
//
#include <hip/hip_runtime.h>
#include <hip/hip_bf16.h>
#include <math.h>

#define D 128
#define TM 64
#define TK 32

// ---------------- graph build ----------------

__global__ void zero_i32(int* __restrict__ p, int n) {
    int i = blockIdx.x * blockDim.x + threadIdx.x;
    if (i < n) p[i] = 0;
}

__global__ void count_kernel(const int* __restrict__ dst, int* __restrict__ cnt, int E) {
    int e = blockIdx.x * blockDim.x + threadIdx.x;
    if (e < E) atomicAdd(&cnt[dst[e]], 1);
}

// single-block exclusive scan over cnt[N] -> rowptr[N+1], cursor[N]; also dinv[i]=rsqrt(cnt[i]+1)
__global__ __launch_bounds__(1024) void scan_kernel(const int* __restrict__ cnt,
                                                    int* __restrict__ rowptr,
                                                    int* __restrict__ cursor,
                                                    float* __restrict__ dinv,
                                                    int N) {
    __shared__ int wsum[16];
    __shared__ int carry_s;
    int tid  = threadIdx.x;
    int lane = tid & 63;
    int wid  = tid >> 6;
    if (tid == 0) carry_s = 0;
    __syncthreads();
    for (int base = 0; base < N; base += 1024) {
        int i = base + tid;
        int v = (i < N) ? cnt[i] : 0;
        // inclusive scan within wave (64)
        int sc = v;
        #pragma unroll
        for (int off = 1; off < 64; off <<= 1) {
            int t = __shfl_up(sc, off, 64);
            if (lane >= off) sc += t;
        }
        if (lane == 63) wsum[wid] = sc;
        __syncthreads();
        if (tid < 16) {
            int w = wsum[tid];
            #pragma unroll
            for (int off = 1; off < 16; off <<= 1) {
                int t = __shfl_up(w, off, 64);
                if (tid >= off) w += t;
            }
            wsum[tid] = w;  // inclusive wave-sum scan
        }
        __syncthreads();
        int waveoff = (wid > 0) ? wsum[wid - 1] : 0;
        int excl = carry_s + waveoff + sc - v;
        if (i < N) {
            rowptr[i] = excl;
            cursor[i] = excl;
            dinv[i]   = rsqrtf((float)v + 1.0f);
        }
        __syncthreads();
        if (tid == 0) carry_s += wsum[15];
        __syncthreads();
    }
    if (tid == 0) rowptr[N] = carry_s;
}

__global__ void fill_kernel(const int* __restrict__ src, const int* __restrict__ dst,
                            int* __restrict__ cursor, int* __restrict__ col, int E) {
    int e = blockIdx.x * blockDim.x + threadIdx.x;
    if (e < E) {
        int d = dst[e];
        int p = atomicAdd(&cursor[d], 1);
        col[p] = src[e];
    }
}

// ---------------- GEMM: Y[i] = dinv[i] * (act(X[i]) @ W) ----------------
// X:[M,128] W:[128,128] Y:[M,128]; relu applied to X on load if relu!=0

__global__ __launch_bounds__(256) void gemm_scale(const float* __restrict__ X,
                                                  const float* __restrict__ W,
                                                  const float* __restrict__ dinv,
                                                  float* __restrict__ Y,
                                                  int M, int relu) {
    __shared__ float Ws[TK][D];   // 16 KB
    __shared__ float Xs[TM][TK];  // 8 KB
    int tid  = threadIdx.x;
    int tx   = tid & 31;   // col group: cols tx*4 .. tx*4+3
    int ty   = tid >> 5;   // 0..7 -> rows ty + 8*i
    int row0 = blockIdx.x * TM;

    float acc[8][4];
    #pragma unroll
    for (int i = 0; i < 8; ++i)
        #pragma unroll
        for (int j = 0; j < 4; ++j) acc[i][j] = 0.0f;

    for (int k0 = 0; k0 < D; k0 += TK) {
        // stage W[k0..k0+TK)[0..D): 1024 float4, 4 per thread
        #pragma unroll
        for (int i = 0; i < 4; ++i) {
            int idx = tid + i * 256;
            int kk  = idx >> 5;
            int jj  = idx & 31;
            float4 w4 = ((const float4*)(W + (size_t)(k0 + kk) * D))[jj];
            ((float4*)&Ws[kk][0])[jj] = w4;
        }
        // stage X[row0..row0+TM)[k0..k0+TK): 512 float4, 2 per thread
        #pragma unroll
        for (int i = 0; i < 2; ++i) {
            int idx = tid + i * 256;
            int r   = idx >> 3;
            int c   = idx & 7;
            int row = row0 + r;
            float4 xv = make_float4(0.f, 0.f, 0.f, 0.f);
            if (row < M) xv = ((const float4*)(X + (size_t)row * D + k0))[c];
            if (relu) {
                xv.x = fmaxf(xv.x, 0.f); xv.y = fmaxf(xv.y, 0.f);
                xv.z = fmaxf(xv.z, 0.f); xv.w = fmaxf(xv.w, 0.f);
            }
            ((float4*)&Xs[r][0])[c] = xv;
        }
        __syncthreads();
        #pragma unroll
        for (int kk = 0; kk < TK; ++kk) {
            float4 w4 = ((const float4*)&Ws[kk][0])[tx];
            #pragma unroll
            for (int i = 0; i < 8; ++i) {
                float xv = Xs[ty + 8 * i][kk];
                acc[i][0] += xv * w4.x;
                acc[i][1] += xv * w4.y;
                acc[i][2] += xv * w4.z;
                acc[i][3] += xv * w4.w;
            }
        }
        __syncthreads();
    }
    #pragma unroll
    for (int i = 0; i < 8; ++i) {
        int row = row0 + ty + 8 * i;
        if (row < M) {
            float s = dinv[row];
            float4 o = make_float4(acc[i][0] * s, acc[i][1] * s, acc[i][2] * s, acc[i][3] * s);
            ((float4*)(Y + (size_t)row * D))[tx] = o;
        }
    }
}

// ---------------- aggregation: out[i] = b + dinv[i]*(ys[i] + sum ys[col]) ----------------
// one wave (64 lanes) per node, float2 per lane

__global__ __launch_bounds__(256) void aggregate_kernel(const float* __restrict__ ys,
                                                        const int* __restrict__ rowptr,
                                                        const int* __restrict__ col,
                                                        const float* __restrict__ dinv,
                                                        const float* __restrict__ b,
                                                        float* __restrict__ out,
                                                        int N) {
    int gwave = (blockIdx.x * blockDim.x + threadIdx.x) >> 6;
    int lane  = threadIdx.x & 63;
    if (gwave >= N) return;
    int row = gwave;

    float2 acc = ((const float2*)(ys + (size_t)row * D))[lane];  // self-loop term
    int s = rowptr[row], e = rowptr[row + 1];
    for (int i = s; i < e; ++i) {
        int c = col[i];
        float2 v = ((const float2*)(ys + (size_t)c * D))[lane];
        acc.x += v.x;
        acc.y += v.y;
    }
    float dv  = dinv[row];
    float2 bb = ((const float2*)b)[lane];
    float2 o  = make_float2(bb.x + dv * acc.x, bb.y + dv * acc.y);
    ((float2*)(out + (size_t)row * D))[lane] = o;
}

// ---------------- launch ----------------

extern "C" void kernel_launch(void* const* d_in, const int* in_sizes, int n_in,
                              void* d_out, int out_size, void* d_ws, size_t ws_size,
                              hipStream_t stream) {
    const float* x   = (const float*)d_in[0];
    const int*   ei  = (const int*)d_in[1];
    const float* W1  = (const float*)d_in[2];
    const float* b1  = (const float*)d_in[3];
    const float* W2  = (const float*)d_in[4];
    const float* b2  = (const float*)d_in[5];
    const float* W3  = (const float*)d_in[6];
    const float* b3  = (const float*)d_in[7];
    float* out = (float*)d_out;

    const int N = in_sizes[0] / D;
    const int E = in_sizes[1] / 2;
    const int* src = ei;
    const int* dst = ei + E;

    // workspace layout (256B aligned chunks)
    char* ws = (char*)d_ws;
    size_t off = 0;
    auto alloc = [&](size_t bytes) {
        void* p = ws + off;
        off = (off + bytes + 255) & ~(size_t)255;
        return p;
    };
    float* ys     = (float*)alloc((size_t)N * D * sizeof(float));
    int*   cnt    = (int*)alloc((size_t)N * sizeof(int));
    int*   rowptr = (int*)alloc((size_t)(N + 1) * sizeof(int));
    int*   cursor = (int*)alloc((size_t)N * sizeof(int));
    float* dinv   = (float*)alloc((size_t)N * sizeof(float));
    int*   col    = (int*)alloc((size_t)E * sizeof(int));
    (void)ws_size; (void)n_in; (void)out_size;

    // ---- graph build (once; shared by all 3 layers) ----
    zero_i32<<<(N + 255) / 256, 256, 0, stream>>>(cnt, N);
    count_kernel<<<(E + 255) / 256, 256, 0, stream>>>(dst, cnt, E);
    scan_kernel<<<1, 1024, 0, stream>>>(cnt, rowptr, cursor, dinv, N);
    fill_kernel<<<(E + 255) / 256, 256, 0, stream>>>(src, dst, cursor, col, E);

    const int gemm_grid = (N + TM - 1) / TM;
    const int agg_grid  = (N * 64 + 255) / 256;

    // layer 1: ys = dinv*(x@W1); out = b1 + dinv*(ys_self + sum)
    gemm_scale<<<gemm_grid, 256, 0, stream>>>(x, W1, dinv, ys, N, 0);
    aggregate_kernel<<<agg_grid, 256, 0, stream>>>(ys, rowptr, col, dinv, b1, out, N);
    // layer 2 (relu on input)
    gemm_scale<<<gemm_grid, 256, 0, stream>>>(out, W2, dinv, ys, N, 1);
    aggregate_kernel<<<agg_grid, 256, 0, stream>>>(ys, rowptr, col, dinv, b2, out, N);
    // layer 3 (relu on input, no relu on output)
    gemm_scale<<<gemm_grid, 256, 0, stream>>>(out, W3, dinv, ys, N, 1);
    aggregate_kernel<<<agg_grid, 256, 0, stream>>>(ys, rowptr, col, dinv, b3, out, N);
}

// Round 2
// 431.504 us; speedup vs baseline: 1.3185x; 1.3185x over previous
//
#include <hip/hip_runtime.h>
#include <hip/hip_bf16.h>
#include <hip/hip_fp16.h>
#include <math.h>

#define D 128
#define TM 64
#define TK 32
#define XPAD 36  // 36 floats = 144 B, 16B-aligned rows, conflict-free across ty groups

// ---------------- graph build ----------------

__global__ void zero_i32(int* __restrict__ p, int n) {
    int i = blockIdx.x * blockDim.x + threadIdx.x;
    if (i < n) p[i] = 0;
}

__global__ void count_kernel(const int* __restrict__ dst, int* __restrict__ cnt, int E) {
    int e = blockIdx.x * blockDim.x + threadIdx.x;
    if (e < E) atomicAdd(&cnt[dst[e]], 1);
}

// single-block exclusive scan over cnt[N] -> rowptr[N+1], cursor[N]; also dinv[i]=rsqrt(cnt[i]+1)
__global__ __launch_bounds__(1024) void scan_kernel(const int* __restrict__ cnt,
                                                    int* __restrict__ rowptr,
                                                    int* __restrict__ cursor,
                                                    float* __restrict__ dinv,
                                                    int N) {
    __shared__ int wsum[16];
    __shared__ int carry_s;
    int tid  = threadIdx.x;
    int lane = tid & 63;
    int wid  = tid >> 6;
    if (tid == 0) carry_s = 0;
    __syncthreads();
    for (int base = 0; base < N; base += 1024) {
        int i = base + tid;
        int v = (i < N) ? cnt[i] : 0;
        int sc = v;
        #pragma unroll
        for (int off = 1; off < 64; off <<= 1) {
            int t = __shfl_up(sc, off, 64);
            if (lane >= off) sc += t;
        }
        if (lane == 63) wsum[wid] = sc;
        __syncthreads();
        if (tid < 16) {
            int w = wsum[tid];
            #pragma unroll
            for (int off = 1; off < 16; off <<= 1) {
                int t = __shfl_up(w, off, 64);
                if (tid >= off) w += t;
            }
            wsum[tid] = w;
        }
        __syncthreads();
        int waveoff = (wid > 0) ? wsum[wid - 1] : 0;
        int excl = carry_s + waveoff + sc - v;
        if (i < N) {
            rowptr[i] = excl;
            cursor[i] = excl;
            dinv[i]   = rsqrtf((float)v + 1.0f);
        }
        __syncthreads();
        if (tid == 0) carry_s += wsum[15];
        __syncthreads();
    }
    if (tid == 0) rowptr[N] = carry_s;
}

__global__ void fill_kernel(const int* __restrict__ src, const int* __restrict__ dst,
                            int* __restrict__ cursor, int* __restrict__ col, int E) {
    int e = blockIdx.x * blockDim.x + threadIdx.x;
    if (e < E) {
        int d = dst[e];
        int p = atomicAdd(&cursor[d], 1);
        col[p] = src[e];
    }
}

// ---------------- GEMM: Y[i] = (half) dinv[i] * (act(X[i]) @ W) ----------------

__global__ __launch_bounds__(256) void gemm_scale(const float* __restrict__ X,
                                                  const float* __restrict__ W,
                                                  const float* __restrict__ dinv,
                                                  __half* __restrict__ Y,
                                                  int M, int relu) {
    __shared__ float Ws[TK][D];     // 16 KB
    __shared__ float Xs[TM][XPAD];  // 9 KB
    int tid  = threadIdx.x;
    int tx   = tid & 31;   // cols tx*4 .. tx*4+3
    int ty   = tid >> 5;   // rows ty + 8*i
    int row0 = blockIdx.x * TM;

    float acc[8][4];
    #pragma unroll
    for (int i = 0; i < 8; ++i)
        #pragma unroll
        for (int j = 0; j < 4; ++j) acc[i][j] = 0.0f;

    for (int k0 = 0; k0 < D; k0 += TK) {
        #pragma unroll
        for (int i = 0; i < 4; ++i) {
            int idx = tid + i * 256;
            int kk  = idx >> 5;
            int jj  = idx & 31;
            float4 w4 = ((const float4*)(W + (size_t)(k0 + kk) * D))[jj];
            ((float4*)&Ws[kk][0])[jj] = w4;
        }
        #pragma unroll
        for (int i = 0; i < 2; ++i) {
            int idx = tid + i * 256;
            int r   = idx >> 3;
            int c   = idx & 7;
            int row = row0 + r;
            float4 xv = make_float4(0.f, 0.f, 0.f, 0.f);
            if (row < M) xv = ((const float4*)(X + (size_t)row * D + k0))[c];
            if (relu) {
                xv.x = fmaxf(xv.x, 0.f); xv.y = fmaxf(xv.y, 0.f);
                xv.z = fmaxf(xv.z, 0.f); xv.w = fmaxf(xv.w, 0.f);
            }
            ((float4*)&Xs[r][0])[c] = xv;
        }
        __syncthreads();
        #pragma unroll
        for (int kk = 0; kk < TK; kk += 4) {
            float4 xr[8];
            #pragma unroll
            for (int i = 0; i < 8; ++i)
                xr[i] = *(const float4*)&Xs[ty + 8 * i][kk];
            #pragma unroll
            for (int t = 0; t < 4; ++t) {
                float4 w4 = ((const float4*)&Ws[kk + t][0])[tx];
                #pragma unroll
                for (int i = 0; i < 8; ++i) {
                    float xv = (t == 0) ? xr[i].x : (t == 1) ? xr[i].y
                             : (t == 2) ? xr[i].z : xr[i].w;
                    acc[i][0] += xv * w4.x;
                    acc[i][1] += xv * w4.y;
                    acc[i][2] += xv * w4.z;
                    acc[i][3] += xv * w4.w;
                }
            }
        }
        __syncthreads();
    }
    #pragma unroll
    for (int i = 0; i < 8; ++i) {
        int row = row0 + ty + 8 * i;
        if (row < M) {
            float s = dinv[row];
            __half2 h0 = __floats2half2_rn(acc[i][0] * s, acc[i][1] * s);
            __half2 h1 = __floats2half2_rn(acc[i][2] * s, acc[i][3] * s);
            uint2 pk;
            pk.x = *(unsigned int*)&h0;
            pk.y = *(unsigned int*)&h1;
            ((uint2*)(Y + (size_t)row * D))[tx] = pk;
        }
    }
}

// ---------------- aggregation: out[i] = b + dinv[i]*(ys[i] + sum ys[col]) ----------------
// one wave per node, half2 per lane; 4x unrolled gather for MLP

__global__ __launch_bounds__(256) void aggregate_kernel(const __half* __restrict__ ys,
                                                        const int* __restrict__ rowptr,
                                                        const int* __restrict__ col,
                                                        const float* __restrict__ dinv,
                                                        const float* __restrict__ b,
                                                        float* __restrict__ out,
                                                        int N) {
    int gwave = (blockIdx.x * blockDim.x + threadIdx.x) >> 6;
    int lane  = threadIdx.x & 63;
    if (gwave >= N) return;
    int row = gwave;

    __half2 hself = ((const __half2*)(ys + (size_t)row * D))[lane];
    float2 acc = make_float2(__low2float(hself), __high2float(hself));
    float2 a1 = make_float2(0.f, 0.f);
    float2 a2 = make_float2(0.f, 0.f);
    float2 a3 = make_float2(0.f, 0.f);

    int s = rowptr[row], e = rowptr[row + 1];
    int i = s;
    for (; i + 4 <= e; i += 4) {
        int c0 = col[i], c1 = col[i + 1], c2 = col[i + 2], c3 = col[i + 3];
        __half2 v0 = ((const __half2*)(ys + (size_t)c0 * D))[lane];
        __half2 v1 = ((const __half2*)(ys + (size_t)c1 * D))[lane];
        __half2 v2 = ((const __half2*)(ys + (size_t)c2 * D))[lane];
        __half2 v3 = ((const __half2*)(ys + (size_t)c3 * D))[lane];
        acc.x += __low2float(v0); acc.y += __high2float(v0);
        a1.x  += __low2float(v1); a1.y  += __high2float(v1);
        a2.x  += __low2float(v2); a2.y  += __high2float(v2);
        a3.x  += __low2float(v3); a3.y  += __high2float(v3);
    }
    for (; i < e; ++i) {
        int c = col[i];
        __half2 v = ((const __half2*)(ys + (size_t)c * D))[lane];
        acc.x += __low2float(v); acc.y += __high2float(v);
    }
    acc.x += a1.x + a2.x + a3.x;
    acc.y += a1.y + a2.y + a3.y;

    float dv  = dinv[row];
    float2 bb = ((const float2*)b)[lane];
    float2 o  = make_float2(bb.x + dv * acc.x, bb.y + dv * acc.y);
    ((float2*)(out + (size_t)row * D))[lane] = o;
}

// ---------------- launch ----------------

extern "C" void kernel_launch(void* const* d_in, const int* in_sizes, int n_in,
                              void* d_out, int out_size, void* d_ws, size_t ws_size,
                              hipStream_t stream) {
    const float* x   = (const float*)d_in[0];
    const int*   ei  = (const int*)d_in[1];
    const float* W1  = (const float*)d_in[2];
    const float* b1  = (const float*)d_in[3];
    const float* W2  = (const float*)d_in[4];
    const float* b2  = (const float*)d_in[5];
    const float* W3  = (const float*)d_in[6];
    const float* b3  = (const float*)d_in[7];
    float* out = (float*)d_out;

    const int N = in_sizes[0] / D;
    const int E = in_sizes[1] / 2;
    const int* src = ei;
    const int* dst = ei + E;

    char* ws = (char*)d_ws;
    size_t off = 0;
    auto alloc = [&](size_t bytes) {
        void* p = ws + off;
        off = (off + bytes + 255) & ~(size_t)255;
        return p;
    };
    __half* ys   = (__half*)alloc((size_t)N * D * sizeof(__half));
    int*   cnt    = (int*)alloc((size_t)N * sizeof(int));
    int*   rowptr = (int*)alloc((size_t)(N + 1) * sizeof(int));
    int*   cursor = (int*)alloc((size_t)N * sizeof(int));
    float* dinv   = (float*)alloc((size_t)N * sizeof(float));
    int*   col    = (int*)alloc((size_t)E * sizeof(int));
    (void)ws_size; (void)n_in; (void)out_size;

    zero_i32<<<(N + 255) / 256, 256, 0, stream>>>(cnt, N);
    count_kernel<<<(E + 255) / 256, 256, 0, stream>>>(dst, cnt, E);
    scan_kernel<<<1, 1024, 0, stream>>>(cnt, rowptr, cursor, dinv, N);
    fill_kernel<<<(E + 255) / 256, 256, 0, stream>>>(src, dst, cursor, col, E);

    const int gemm_grid = (N + TM - 1) / TM;
    const int agg_grid  = (N * 64 + 255) / 256;

    gemm_scale<<<gemm_grid, 256, 0, stream>>>(x, W1, dinv, ys, N, 0);
    aggregate_kernel<<<agg_grid, 256, 0, stream>>>(ys, rowptr, col, dinv, b1, out, N);
    gemm_scale<<<gemm_grid, 256, 0, stream>>>(out, W2, dinv, ys, N, 1);
    aggregate_kernel<<<agg_grid, 256, 0, stream>>>(ys, rowptr, col, dinv, b2, out, N);
    gemm_scale<<<gemm_grid, 256, 0, stream>>>(out, W3, dinv, ys, N, 1);
    aggregate_kernel<<<agg_grid, 256, 0, stream>>>(ys, rowptr, col, dinv, b3, out, N);
}

// Round 3
// 403.386 us; speedup vs baseline: 1.4104x; 1.0697x over previous
//
#include <hip/hip_runtime.h>
#include <hip/hip_fp16.h>
#include <math.h>

#define D 128

typedef __attribute__((ext_vector_type(8))) _Float16 half8;
typedef __attribute__((ext_vector_type(4))) float f32x4;

// ---------------- graph build ----------------

__global__ void count_kernel(const int* __restrict__ dst, int* __restrict__ cnt, int E) {
    int e = blockIdx.x * blockDim.x + threadIdx.x;
    if (e < E) atomicAdd(&cnt[dst[e]], 1);  // fire-and-forget (no return) — fast path
}

// single-block exclusive scan over cnt[N] -> rowptr[N+1], cursor[N]; dinv[i]=rsqrt(cnt[i]+1)
__global__ __launch_bounds__(1024) void scan_kernel(const int* __restrict__ cnt,
                                                    int* __restrict__ rowptr,
                                                    int* __restrict__ cursor,
                                                    float* __restrict__ dinv,
                                                    int N) {
    __shared__ int wsum[16];
    __shared__ int carry_s;
    int tid  = threadIdx.x;
    int lane = tid & 63;
    int wid  = tid >> 6;
    if (tid == 0) carry_s = 0;
    __syncthreads();
    for (int base = 0; base < N; base += 1024) {
        int i = base + tid;
        int v = (i < N) ? cnt[i] : 0;
        int sc = v;
        #pragma unroll
        for (int off = 1; off < 64; off <<= 1) {
            int t = __shfl_up(sc, off, 64);
            if (lane >= off) sc += t;
        }
        if (lane == 63) wsum[wid] = sc;
        __syncthreads();
        if (tid < 16) {
            int w = wsum[tid];
            #pragma unroll
            for (int off = 1; off < 16; off <<= 1) {
                int t = __shfl_up(w, off, 64);
                if (tid >= off) w += t;
            }
            wsum[tid] = w;
        }
        __syncthreads();
        int waveoff = (wid > 0) ? wsum[wid - 1] : 0;
        int excl = carry_s + waveoff + sc - v;
        if (i < N) {
            rowptr[i] = excl;
            cursor[i] = excl;
            dinv[i]   = rsqrtf((float)v + 1.0f);
        }
        __syncthreads();
        if (tid == 0) carry_s += wsum[15];
        __syncthreads();
    }
    if (tid == 0) rowptr[N] = carry_s;
}

__global__ void fill_kernel(const int* __restrict__ src, const int* __restrict__ dst,
                            int* __restrict__ cursor, int* __restrict__ col, int E) {
    int e = blockIdx.x * blockDim.x + threadIdx.x;
    if (e < E) {
        int d = dst[e];
        int p = atomicAdd(&cursor[d], 1);
        __builtin_nontemporal_store(src[e], &col[p]);  // no-allocate: avoid per-store line writeback
    }
}

// ---------------- W transpose+convert: WhT[n][k] = (half)W[k][n] ----------------

__global__ void convw_kernel(const float* __restrict__ W, __half* __restrict__ WhT) {
    int i = blockIdx.x * blockDim.x + threadIdx.x;  // 16384
    int n = i >> 7, k = i & 127;
    WhT[(size_t)n * D + k] = __float2half(W[(size_t)k * D + n]);
}

// ---------------- MFMA GEMM: Y[i] = (half) dinv[i] * (act(X[i]) @ W) ----------------
// Zero-LDS: each wave owns 16 rows (16 | M), A-frags straight from global fp32
// (relu+cvt in-register), B-frags from pre-transposed fp16 WhT (L2-hot).
// Layouts (m89/m120 verified): A[m=lane&15][k=quad*8+j]; B[k=quad*8+j][n=lane&15];
// C/D: row=quad*4+reg, col=lane&15.

__global__ __launch_bounds__(256) void gemm_mfma(const float* __restrict__ X,
                                                 const __half* __restrict__ WhT,
                                                 const float* __restrict__ dinv,
                                                 __half* __restrict__ Y,
                                                 int M, int relu) {
    int tid  = threadIdx.x;
    int wave = tid >> 6;
    int lane = tid & 63;
    int quad = lane >> 4;
    int l16  = lane & 15;
    int m0   = blockIdx.x * 64 + wave * 16;
    if (m0 >= M) return;  // 16 | M, so waves are all-in or all-out

    f32x4 acc[8];
    #pragma unroll
    for (int t = 0; t < 8; ++t) acc[t] = (f32x4)0.0f;

    const float* xrow = X + (size_t)(m0 + l16) * D;

    #pragma unroll
    for (int ks = 0; ks < 4; ++ks) {
        int k0 = ks * 32 + quad * 8;
        float4 x0 = *(const float4*)(xrow + k0);
        float4 x1 = *(const float4*)(xrow + k0 + 4);
        if (relu) {
            x0.x = fmaxf(x0.x, 0.f); x0.y = fmaxf(x0.y, 0.f);
            x0.z = fmaxf(x0.z, 0.f); x0.w = fmaxf(x0.w, 0.f);
            x1.x = fmaxf(x1.x, 0.f); x1.y = fmaxf(x1.y, 0.f);
            x1.z = fmaxf(x1.z, 0.f); x1.w = fmaxf(x1.w, 0.f);
        }
        half8 a;
        a[0] = (_Float16)x0.x; a[1] = (_Float16)x0.y;
        a[2] = (_Float16)x0.z; a[3] = (_Float16)x0.w;
        a[4] = (_Float16)x1.x; a[5] = (_Float16)x1.y;
        a[6] = (_Float16)x1.z; a[7] = (_Float16)x1.w;
        #pragma unroll
        for (int t = 0; t < 8; ++t) {
            half8 b = *(const half8*)(WhT + (size_t)(t * 16 + l16) * D + k0);
            acc[t] = __builtin_amdgcn_mfma_f32_16x16x32_f16(a, b, acc[t], 0, 0, 0);
        }
    }

    float4 dv = *(const float4*)(dinv + m0 + quad * 4);
    float dvs[4] = {dv.x, dv.y, dv.z, dv.w};
    #pragma unroll
    for (int t = 0; t < 8; ++t) {
        #pragma unroll
        for (int r = 0; r < 4; ++r) {
            int grow = m0 + quad * 4 + r;
            Y[(size_t)grow * D + t * 16 + l16] = __float2half(acc[t][r] * dvs[r]);
        }
    }
}

// ---------------- aggregation: out[i] = b + dinv[i]*(ys[i] + sum ys[col]) ----------------
// one wave per node; lane-parallel col prefetch + shfl broadcast; 8-deep gather ILP

__global__ __launch_bounds__(256) void aggregate_kernel(const __half* __restrict__ ys,
                                                        const int* __restrict__ rowptr,
                                                        const int* __restrict__ col,
                                                        const float* __restrict__ dinv,
                                                        const float* __restrict__ b,
                                                        float* __restrict__ out,
                                                        int N) {
    int gwave = (blockIdx.x * blockDim.x + threadIdx.x) >> 6;
    int lane  = threadIdx.x & 63;
    if (gwave >= N) return;
    int row = gwave;
    int s = rowptr[row], e = rowptr[row + 1];

    __half2 hself = ((const __half2*)(ys + (size_t)row * D))[lane];
    float2 a0 = __half22float2(hself);
    float2 a1 = make_float2(0.f, 0.f), a2 = make_float2(0.f, 0.f),
           a3 = make_float2(0.f, 0.f), a4 = make_float2(0.f, 0.f),
           a5 = make_float2(0.f, 0.f), a6 = make_float2(0.f, 0.f),
           a7 = make_float2(0.f, 0.f);

    for (int base = s; base < e; base += 64) {
        int idx = base + lane;
        int myc = (idx < e) ? col[idx] : 0;
        int nb  = min(64, e - base);
        int j = 0;
        for (; j + 8 <= nb; j += 8) {
            int c0 = __shfl(myc, j + 0), c1 = __shfl(myc, j + 1);
            int c2 = __shfl(myc, j + 2), c3 = __shfl(myc, j + 3);
            int c4 = __shfl(myc, j + 4), c5 = __shfl(myc, j + 5);
            int c6 = __shfl(myc, j + 6), c7 = __shfl(myc, j + 7);
            __half2 v0 = ((const __half2*)(ys + (size_t)c0 * D))[lane];
            __half2 v1 = ((const __half2*)(ys + (size_t)c1 * D))[lane];
            __half2 v2 = ((const __half2*)(ys + (size_t)c2 * D))[lane];
            __half2 v3 = ((const __half2*)(ys + (size_t)c3 * D))[lane];
            __half2 v4 = ((const __half2*)(ys + (size_t)c4 * D))[lane];
            __half2 v5 = ((const __half2*)(ys + (size_t)c5 * D))[lane];
            __half2 v6 = ((const __half2*)(ys + (size_t)c6 * D))[lane];
            __half2 v7 = ((const __half2*)(ys + (size_t)c7 * D))[lane];
            a0.x += __low2float(v0); a0.y += __high2float(v0);
            a1.x += __low2float(v1); a1.y += __high2float(v1);
            a2.x += __low2float(v2); a2.y += __high2float(v2);
            a3.x += __low2float(v3); a3.y += __high2float(v3);
            a4.x += __low2float(v4); a4.y += __high2float(v4);
            a5.x += __low2float(v5); a5.y += __high2float(v5);
            a6.x += __low2float(v6); a6.y += __high2float(v6);
            a7.x += __low2float(v7); a7.y += __high2float(v7);
        }
        for (; j < nb; ++j) {
            int c = __shfl(myc, j);
            __half2 v = ((const __half2*)(ys + (size_t)c * D))[lane];
            a0.x += __low2float(v); a0.y += __high2float(v);
        }
    }
    a0.x += a1.x + a2.x + a3.x + a4.x + a5.x + a6.x + a7.x;
    a0.y += a1.y + a2.y + a3.y + a4.y + a5.y + a6.y + a7.y;

    float dv  = dinv[row];
    float2 bb = ((const float2*)b)[lane];
    float2 o  = make_float2(bb.x + dv * a0.x, bb.y + dv * a0.y);
    ((float2*)(out + (size_t)row * D))[lane] = o;
}

// ---------------- launch ----------------

extern "C" void kernel_launch(void* const* d_in, const int* in_sizes, int n_in,
                              void* d_out, int out_size, void* d_ws, size_t ws_size,
                              hipStream_t stream) {
    const float* x   = (const float*)d_in[0];
    const int*   ei  = (const int*)d_in[1];
    const float* W1  = (const float*)d_in[2];
    const float* b1  = (const float*)d_in[3];
    const float* W2  = (const float*)d_in[4];
    const float* b2  = (const float*)d_in[5];
    const float* W3  = (const float*)d_in[6];
    const float* b3  = (const float*)d_in[7];
    float* out = (float*)d_out;

    const int N = in_sizes[0] / D;
    const int E = in_sizes[1] / 2;
    const int* src = ei;
    const int* dst = ei + E;

    char* ws = (char*)d_ws;
    size_t off = 0;
    auto alloc = [&](size_t bytes) {
        void* p = ws + off;
        off = (off + bytes + 255) & ~(size_t)255;
        return p;
    };
    __half* ys    = (__half*)alloc((size_t)N * D * sizeof(__half));
    int*   cnt    = (int*)alloc((size_t)N * sizeof(int));
    int*   rowptr = (int*)alloc((size_t)(N + 1) * sizeof(int));
    int*   cursor = (int*)alloc((size_t)N * sizeof(int));
    float* dinv   = (float*)alloc((size_t)N * sizeof(float));
    int*   col    = (int*)alloc((size_t)E * sizeof(int));
    __half* WhT1  = (__half*)alloc((size_t)D * D * sizeof(__half));
    __half* WhT2  = (__half*)alloc((size_t)D * D * sizeof(__half));
    __half* WhT3  = (__half*)alloc((size_t)D * D * sizeof(__half));
    (void)ws_size; (void)n_in; (void)out_size;

    // weight transpose+convert (independent of graph build)
    convw_kernel<<<(D * D + 255) / 256, 256, 0, stream>>>(W1, WhT1);
    convw_kernel<<<(D * D + 255) / 256, 256, 0, stream>>>(W2, WhT2);
    convw_kernel<<<(D * D + 255) / 256, 256, 0, stream>>>(W3, WhT3);

    // graph build (once; shared by all 3 layers)
    hipMemsetAsync(cnt, 0, (size_t)N * sizeof(int), stream);
    count_kernel<<<(E + 255) / 256, 256, 0, stream>>>(dst, cnt, E);
    scan_kernel<<<1, 1024, 0, stream>>>(cnt, rowptr, cursor, dinv, N);
    fill_kernel<<<(E + 255) / 256, 256, 0, stream>>>(src, dst, cursor, col, E);

    const int gemm_grid = (N + 63) / 64;
    const int agg_grid  = (N * 64 + 255) / 256;

    gemm_mfma<<<gemm_grid, 256, 0, stream>>>(x, WhT1, dinv, ys, N, 0);
    aggregate_kernel<<<agg_grid, 256, 0, stream>>>(ys, rowptr, col, dinv, b1, out, N);
    gemm_mfma<<<gemm_grid, 256, 0, stream>>>(out, WhT2, dinv, ys, N, 1);
    aggregate_kernel<<<agg_grid, 256, 0, stream>>>(ys, rowptr, col, dinv, b2, out, N);
    gemm_mfma<<<gemm_grid, 256, 0, stream>>>(out, WhT3, dinv, ys, N, 1);
    aggregate_kernel<<<agg_grid, 256, 0, stream>>>(ys, rowptr, col, dinv, b3, out, N);
}

// Round 4
// 341.049 us; speedup vs baseline: 1.6682x; 1.1828x over previous
//
#include <hip/hip_runtime.h>
#include <hip/hip_fp16.h>
#include <math.h>

#define D 128

typedef __attribute__((ext_vector_type(8))) _Float16 half8;
typedef __attribute__((ext_vector_type(4))) float f32x4;

// ---------------- graph build ----------------

// rank[e] = arrival order of edge e within its dst bucket; cnt[d] = in-degree
__global__ void count_rank_kernel(const int* __restrict__ dst, int* __restrict__ cnt,
                                  int* __restrict__ rank, int E) {
    int e0 = (blockIdx.x * blockDim.x + threadIdx.x) * 4;
    if (e0 + 3 < E) {
        int4 d = *(const int4*)(dst + e0);
        int4 r;
        r.x = atomicAdd(&cnt[d.x], 1);
        r.y = atomicAdd(&cnt[d.y], 1);
        r.z = atomicAdd(&cnt[d.z], 1);
        r.w = atomicAdd(&cnt[d.w], 1);
        *(int4*)(rank + e0) = r;
    } else {
        for (int e = e0; e < E; ++e) rank[e] = atomicAdd(&cnt[dst[e]], 1);
    }
}

// single-block scan, 4 elems/thread: cnt[N] -> rowptr[N+1]; dinv[i]=rsqrt(cnt[i]+1)
__global__ __launch_bounds__(1024) void scan_kernel(const int* __restrict__ cnt,
                                                    int* __restrict__ rowptr,
                                                    float* __restrict__ dinv,
                                                    int N) {
    __shared__ int wsum[16];
    __shared__ int carry_s;
    int tid  = threadIdx.x;
    int lane = tid & 63;
    int wid  = tid >> 6;
    if (tid == 0) carry_s = 0;
    __syncthreads();
    for (int base = 0; base < N; base += 4096) {
        int i = base + tid * 4;
        int4 v = make_int4(0, 0, 0, 0);
        if (i + 3 < N) v = *(const int4*)(cnt + i);
        else {
            if (i + 0 < N) v.x = cnt[i + 0];
            if (i + 1 < N) v.y = cnt[i + 1];
            if (i + 2 < N) v.z = cnt[i + 2];
            if (i + 3 < N) v.w = cnt[i + 3];
        }
        int s0 = v.x, s1 = s0 + v.y, s2 = s1 + v.z, s3 = s2 + v.w;  // thread-local incl
        int sc = s3;  // wave inclusive scan of thread sums
        #pragma unroll
        for (int off = 1; off < 64; off <<= 1) {
            int t = __shfl_up(sc, off, 64);
            if (lane >= off) sc += t;
        }
        if (lane == 63) wsum[wid] = sc;
        __syncthreads();
        if (tid < 16) {
            int w = wsum[tid];
            #pragma unroll
            for (int off = 1; off < 16; off <<= 1) {
                int t = __shfl_up(w, off, 64);
                if (tid >= off) w += t;
            }
            wsum[tid] = w;
        }
        __syncthreads();
        int waveoff = (wid > 0) ? wsum[wid - 1] : 0;
        int excl = carry_s + waveoff + (sc - s3);  // exclusive base for this thread
        if (i + 0 < N) { rowptr[i + 0] = excl;      dinv[i + 0] = rsqrtf((float)v.x + 1.0f); }
        if (i + 1 < N) { rowptr[i + 1] = excl + s0; dinv[i + 1] = rsqrtf((float)v.y + 1.0f); }
        if (i + 2 < N) { rowptr[i + 2] = excl + s1; dinv[i + 2] = rsqrtf((float)v.z + 1.0f); }
        if (i + 3 < N) { rowptr[i + 3] = excl + s2; dinv[i + 3] = rsqrtf((float)v.w + 1.0f); }
        __syncthreads();
        if (tid == 0) carry_s += wsum[15];
        __syncthreads();
    }
    if (tid == 0) rowptr[N] = carry_s;
}

// atomic-free scatter: col[rowptr[dst[e]] + rank[e]] = src[e]
__global__ void fill_kernel(const int* __restrict__ src, const int* __restrict__ dst,
                            const int* __restrict__ rank, const int* __restrict__ rowptr,
                            int* __restrict__ col, int E) {
    int e0 = (blockIdx.x * blockDim.x + threadIdx.x) * 4;
    if (e0 + 3 < E) {
        int4 d = *(const int4*)(dst + e0);
        int4 r = *(const int4*)(rank + e0);
        int4 s = *(const int4*)(src + e0);
        int p0 = rowptr[d.x] + r.x;
        int p1 = rowptr[d.y] + r.y;
        int p2 = rowptr[d.z] + r.z;
        int p3 = rowptr[d.w] + r.w;
        col[p0] = s.x;
        col[p1] = s.y;
        col[p2] = s.z;
        col[p3] = s.w;
    } else {
        for (int e = e0; e < E; ++e) col[rowptr[dst[e]] + rank[e]] = src[e];
    }
}

// ---------------- W transpose+convert: WhT[l][n][k] = (half)Wl[k][n], 3 layers ----------------

__global__ void convw_kernel(const float* __restrict__ W1, const float* __restrict__ W2,
                             const float* __restrict__ W3, __half* __restrict__ WhT) {
    int i = blockIdx.x * blockDim.x + threadIdx.x;  // 3*16384
    int l = i >> 14;
    int j = i & 16383;
    int n = j >> 7, k = j & 127;
    const float* W = (l == 0) ? W1 : (l == 1) ? W2 : W3;
    WhT[(size_t)i] = __float2half(W[(size_t)k * D + n]);
    // layout: WhT + l*16384 is [n][k]
}

// ---------------- MFMA GEMM: Y[i] = (half) dinv[i] * (act(X[i]) @ W) ----------------
// Zero-LDS: wave owns 16 rows; A from global fp32 (relu+cvt in-reg); B from fp16 WhT (L2-hot).
// Layouts: A[m=lane&15][k=quad*8+j]; B[k=quad*8+j][n=lane&15]; C/D row=quad*4+reg, col=lane&15.

__global__ __launch_bounds__(256) void gemm_mfma(const float* __restrict__ X,
                                                 const __half* __restrict__ WhT,
                                                 const float* __restrict__ dinv,
                                                 __half* __restrict__ Y,
                                                 int M, int relu) {
    int tid  = threadIdx.x;
    int wave = tid >> 6;
    int lane = tid & 63;
    int quad = lane >> 4;
    int l16  = lane & 15;
    int m0   = blockIdx.x * 64 + wave * 16;
    if (m0 >= M) return;

    f32x4 acc[8];
    #pragma unroll
    for (int t = 0; t < 8; ++t) acc[t] = (f32x4)0.0f;

    const float* xrow = X + (size_t)(m0 + l16) * D;

    #pragma unroll
    for (int ks = 0; ks < 4; ++ks) {
        int k0 = ks * 32 + quad * 8;
        float4 x0 = *(const float4*)(xrow + k0);
        float4 x1 = *(const float4*)(xrow + k0 + 4);
        if (relu) {
            x0.x = fmaxf(x0.x, 0.f); x0.y = fmaxf(x0.y, 0.f);
            x0.z = fmaxf(x0.z, 0.f); x0.w = fmaxf(x0.w, 0.f);
            x1.x = fmaxf(x1.x, 0.f); x1.y = fmaxf(x1.y, 0.f);
            x1.z = fmaxf(x1.z, 0.f); x1.w = fmaxf(x1.w, 0.f);
        }
        half8 a;
        a[0] = (_Float16)x0.x; a[1] = (_Float16)x0.y;
        a[2] = (_Float16)x0.z; a[3] = (_Float16)x0.w;
        a[4] = (_Float16)x1.x; a[5] = (_Float16)x1.y;
        a[6] = (_Float16)x1.z; a[7] = (_Float16)x1.w;
        #pragma unroll
        for (int t = 0; t < 8; ++t) {
            half8 b = *(const half8*)(WhT + (size_t)(t * 16 + l16) * D + k0);
            acc[t] = __builtin_amdgcn_mfma_f32_16x16x32_f16(a, b, acc[t], 0, 0, 0);
        }
    }

    float4 dv = *(const float4*)(dinv + m0 + quad * 4);
    float dvs[4] = {dv.x, dv.y, dv.z, dv.w};
    #pragma unroll
    for (int t = 0; t < 8; ++t) {
        #pragma unroll
        for (int r = 0; r < 4; ++r) {
            int grow = m0 + quad * 4 + r;
            Y[(size_t)grow * D + t * 16 + l16] = __float2half(acc[t][r] * dvs[r]);
        }
    }
}

// ---------------- aggregation: out[i] = b + dinv[i]*(ys[i] + sum ys[col]) ----------------

__global__ __launch_bounds__(256) void aggregate_kernel(const __half* __restrict__ ys,
                                                        const int* __restrict__ rowptr,
                                                        const int* __restrict__ col,
                                                        const float* __restrict__ dinv,
                                                        const float* __restrict__ b,
                                                        float* __restrict__ out,
                                                        int N) {
    int gwave = (blockIdx.x * blockDim.x + threadIdx.x) >> 6;
    int lane  = threadIdx.x & 63;
    if (gwave >= N) return;
    int row = gwave;
    int s = rowptr[row], e = rowptr[row + 1];

    __half2 hself = ((const __half2*)(ys + (size_t)row * D))[lane];
    float2 a0 = __half22float2(hself);
    float2 a1 = make_float2(0.f, 0.f), a2 = make_float2(0.f, 0.f),
           a3 = make_float2(0.f, 0.f), a4 = make_float2(0.f, 0.f),
           a5 = make_float2(0.f, 0.f), a6 = make_float2(0.f, 0.f),
           a7 = make_float2(0.f, 0.f);

    for (int base = s; base < e; base += 64) {
        int idx = base + lane;
        int myc = (idx < e) ? col[idx] : 0;
        int nb  = min(64, e - base);
        int j = 0;
        for (; j + 8 <= nb; j += 8) {
            int c0 = __shfl(myc, j + 0), c1 = __shfl(myc, j + 1);
            int c2 = __shfl(myc, j + 2), c3 = __shfl(myc, j + 3);
            int c4 = __shfl(myc, j + 4), c5 = __shfl(myc, j + 5);
            int c6 = __shfl(myc, j + 6), c7 = __shfl(myc, j + 7);
            __half2 v0 = ((const __half2*)(ys + (size_t)c0 * D))[lane];
            __half2 v1 = ((const __half2*)(ys + (size_t)c1 * D))[lane];
            __half2 v2 = ((const __half2*)(ys + (size_t)c2 * D))[lane];
            __half2 v3 = ((const __half2*)(ys + (size_t)c3 * D))[lane];
            __half2 v4 = ((const __half2*)(ys + (size_t)c4 * D))[lane];
            __half2 v5 = ((const __half2*)(ys + (size_t)c5 * D))[lane];
            __half2 v6 = ((const __half2*)(ys + (size_t)c6 * D))[lane];
            __half2 v7 = ((const __half2*)(ys + (size_t)c7 * D))[lane];
            a0.x += __low2float(v0); a0.y += __high2float(v0);
            a1.x += __low2float(v1); a1.y += __high2float(v1);
            a2.x += __low2float(v2); a2.y += __high2float(v2);
            a3.x += __low2float(v3); a3.y += __high2float(v3);
            a4.x += __low2float(v4); a4.y += __high2float(v4);
            a5.x += __low2float(v5); a5.y += __high2float(v5);
            a6.x += __low2float(v6); a6.y += __high2float(v6);
            a7.x += __low2float(v7); a7.y += __high2float(v7);
        }
        for (; j < nb; ++j) {
            int c = __shfl(myc, j);
            __half2 v = ((const __half2*)(ys + (size_t)c * D))[lane];
            a0.x += __low2float(v); a0.y += __high2float(v);
        }
    }
    a0.x += a1.x + a2.x + a3.x + a4.x + a5.x + a6.x + a7.x;
    a0.y += a1.y + a2.y + a3.y + a4.y + a5.y + a6.y + a7.y;

    float dv  = dinv[row];
    float2 bb = ((const float2*)b)[lane];
    float2 o  = make_float2(bb.x + dv * a0.x, bb.y + dv * a0.y);
    ((float2*)(out + (size_t)row * D))[lane] = o;
}

// ---------------- launch ----------------

extern "C" void kernel_launch(void* const* d_in, const int* in_sizes, int n_in,
                              void* d_out, int out_size, void* d_ws, size_t ws_size,
                              hipStream_t stream) {
    const float* x   = (const float*)d_in[0];
    const int*   ei  = (const int*)d_in[1];
    const float* W1  = (const float*)d_in[2];
    const float* b1  = (const float*)d_in[3];
    const float* W2  = (const float*)d_in[4];
    const float* b2  = (const float*)d_in[5];
    const float* W3  = (const float*)d_in[6];
    const float* b3  = (const float*)d_in[7];
    float* out = (float*)d_out;

    const int N = in_sizes[0] / D;
    const int E = in_sizes[1] / 2;
    const int* src = ei;
    const int* dst = ei + E;

    char* ws = (char*)d_ws;
    size_t off = 0;
    auto alloc = [&](size_t bytes) {
        void* p = ws + off;
        off = (off + bytes + 255) & ~(size_t)255;
        return p;
    };
    __half* ys    = (__half*)alloc((size_t)N * D * sizeof(__half));
    int*   cnt    = (int*)alloc((size_t)N * sizeof(int));
    int*   rowptr = (int*)alloc((size_t)(N + 1) * sizeof(int));
    float* dinv   = (float*)alloc((size_t)N * sizeof(float));
    int*   rank   = (int*)alloc((size_t)E * sizeof(int));
    int*   col    = (int*)alloc((size_t)E * sizeof(int));
    __half* WhT   = (__half*)alloc((size_t)3 * D * D * sizeof(__half));
    (void)ws_size; (void)n_in; (void)out_size;

    convw_kernel<<<(3 * D * D + 255) / 256, 256, 0, stream>>>(W1, W2, W3, WhT);

    hipMemsetAsync(cnt, 0, (size_t)N * sizeof(int), stream);
    count_rank_kernel<<<(E / 4 + 255) / 256, 256, 0, stream>>>(dst, cnt, rank, E);
    scan_kernel<<<1, 1024, 0, stream>>>(cnt, rowptr, dinv, N);
    fill_kernel<<<(E / 4 + 255) / 256, 256, 0, stream>>>(src, dst, rank, rowptr, col, E);

    const int gemm_grid = (N + 63) / 64;
    const int agg_grid  = (N * 64 + 255) / 256;

    gemm_mfma<<<gemm_grid, 256, 0, stream>>>(x, WhT, dinv, ys, N, 0);
    aggregate_kernel<<<agg_grid, 256, 0, stream>>>(ys, rowptr, col, dinv, b1, out, N);
    gemm_mfma<<<gemm_grid, 256, 0, stream>>>(out, WhT + 16384, dinv, ys, N, 1);
    aggregate_kernel<<<agg_grid, 256, 0, stream>>>(ys, rowptr, col, dinv, b2, out, N);
    gemm_mfma<<<gemm_grid, 256, 0, stream>>>(out, WhT + 32768, dinv, ys, N, 1);
    aggregate_kernel<<<agg_grid, 256, 0, stream>>>(ys, rowptr, col, dinv, b3, out, N);
}

// Round 5
// 334.453 us; speedup vs baseline: 1.7011x; 1.0197x over previous
//
#include <hip/hip_runtime.h>
#include <hip/hip_fp16.h>
#include <math.h>

#define D 128

typedef __attribute__((ext_vector_type(8))) _Float16 half8;
typedef __attribute__((ext_vector_type(4))) float f32x4;

// ---------------- graph build ----------------

// rank[e] = arrival order of edge e within its dst bucket; cnt[d] = in-degree
__global__ void count_rank_kernel(const int* __restrict__ dst, int* __restrict__ cnt,
                                  int* __restrict__ rank, int E) {
    int e0 = (blockIdx.x * blockDim.x + threadIdx.x) * 8;
    if (e0 + 7 < E) {
        int4 da = *(const int4*)(dst + e0);
        int4 db = *(const int4*)(dst + e0 + 4);
        int4 ra, rb;
        ra.x = atomicAdd(&cnt[da.x], 1);
        ra.y = atomicAdd(&cnt[da.y], 1);
        ra.z = atomicAdd(&cnt[da.z], 1);
        ra.w = atomicAdd(&cnt[da.w], 1);
        rb.x = atomicAdd(&cnt[db.x], 1);
        rb.y = atomicAdd(&cnt[db.y], 1);
        rb.z = atomicAdd(&cnt[db.z], 1);
        rb.w = atomicAdd(&cnt[db.w], 1);
        *(int4*)(rank + e0)     = ra;
        *(int4*)(rank + e0 + 4) = rb;
    } else {
        for (int e = e0; e < E; ++e) rank[e] = atomicAdd(&cnt[dst[e]], 1);
    }
}

// single-block scan, 4 elems/thread: cnt[N] -> rowptr[N+1]; dinv[i]=rsqrt(cnt[i]+1)
__global__ __launch_bounds__(1024) void scan_kernel(const int* __restrict__ cnt,
                                                    int* __restrict__ rowptr,
                                                    float* __restrict__ dinv,
                                                    int N) {
    __shared__ int wsum[16];
    __shared__ int carry_s;
    int tid  = threadIdx.x;
    int lane = tid & 63;
    int wid  = tid >> 6;
    if (tid == 0) carry_s = 0;
    __syncthreads();
    for (int base = 0; base < N; base += 4096) {
        int i = base + tid * 4;
        int4 v = make_int4(0, 0, 0, 0);
        if (i + 3 < N) v = *(const int4*)(cnt + i);
        else {
            if (i + 0 < N) v.x = cnt[i + 0];
            if (i + 1 < N) v.y = cnt[i + 1];
            if (i + 2 < N) v.z = cnt[i + 2];
            if (i + 3 < N) v.w = cnt[i + 3];
        }
        int s0 = v.x, s1 = s0 + v.y, s2 = s1 + v.z, s3 = s2 + v.w;
        int sc = s3;
        #pragma unroll
        for (int off = 1; off < 64; off <<= 1) {
            int t = __shfl_up(sc, off, 64);
            if (lane >= off) sc += t;
        }
        if (lane == 63) wsum[wid] = sc;
        __syncthreads();
        if (tid < 16) {
            int w = wsum[tid];
            #pragma unroll
            for (int off = 1; off < 16; off <<= 1) {
                int t = __shfl_up(w, off, 64);
                if (tid >= off) w += t;
            }
            wsum[tid] = w;
        }
        __syncthreads();
        int waveoff = (wid > 0) ? wsum[wid - 1] : 0;
        int excl = carry_s + waveoff + (sc - s3);
        if (i + 0 < N) { rowptr[i + 0] = excl;      dinv[i + 0] = rsqrtf((float)v.x + 1.0f); }
        if (i + 1 < N) { rowptr[i + 1] = excl + s0; dinv[i + 1] = rsqrtf((float)v.y + 1.0f); }
        if (i + 2 < N) { rowptr[i + 2] = excl + s1; dinv[i + 2] = rsqrtf((float)v.z + 1.0f); }
        if (i + 3 < N) { rowptr[i + 3] = excl + s2; dinv[i + 3] = rsqrtf((float)v.w + 1.0f); }
        __syncthreads();
        if (tid == 0) carry_s += wsum[15];
        __syncthreads();
    }
    if (tid == 0) rowptr[N] = carry_s;
}

// atomic-free scatter: col[rowptr[dst[e]] + rank[e]] = src[e]
__global__ void fill_kernel(const int* __restrict__ src, const int* __restrict__ dst,
                            const int* __restrict__ rank, const int* __restrict__ rowptr,
                            int* __restrict__ col, int E) {
    int e0 = (blockIdx.x * blockDim.x + threadIdx.x) * 8;
    if (e0 + 7 < E) {
        int4 da = *(const int4*)(dst + e0);
        int4 db = *(const int4*)(dst + e0 + 4);
        int4 ra = *(const int4*)(rank + e0);
        int4 rb = *(const int4*)(rank + e0 + 4);
        int4 sa = *(const int4*)(src + e0);
        int4 sb = *(const int4*)(src + e0 + 4);
        int p0 = rowptr[da.x] + ra.x;
        int p1 = rowptr[da.y] + ra.y;
        int p2 = rowptr[da.z] + ra.z;
        int p3 = rowptr[da.w] + ra.w;
        int p4 = rowptr[db.x] + rb.x;
        int p5 = rowptr[db.y] + rb.y;
        int p6 = rowptr[db.z] + rb.z;
        int p7 = rowptr[db.w] + rb.w;
        col[p0] = sa.x; col[p1] = sa.y; col[p2] = sa.z; col[p3] = sa.w;
        col[p4] = sb.x; col[p5] = sb.y; col[p6] = sb.z; col[p7] = sb.w;
    } else {
        for (int e = e0; e < E; ++e) col[rowptr[dst[e]] + rank[e]] = src[e];
    }
}

// ---------------- W transpose+convert: WhT[l][n][k] = (half)Wl[k][n] ----------------

__global__ void convw_kernel(const float* __restrict__ W1, const float* __restrict__ W2,
                             const float* __restrict__ W3, __half* __restrict__ WhT) {
    int i = blockIdx.x * blockDim.x + threadIdx.x;  // 3*16384
    int l = i >> 14;
    int j = i & 16383;
    int n = j >> 7, k = j & 127;
    const float* W = (l == 0) ? W1 : (l == 1) ? W2 : W3;
    WhT[(size_t)i] = __float2half(W[(size_t)k * D + n]);
}

// ---------------- MFMA GEMM: Y[i] = (half) dinv[i] * (X[i] @ W) ----------------
// Zero-LDS: wave owns 16 rows; B from fp16 WhT (L2-hot).
// Layouts: A[m=lane&15][k=quad*8+j]; B[k=quad*8+j][n=lane&15]; C/D row=quad*4+reg, col=lane&15.

__global__ __launch_bounds__(256) void gemm_mfma_f32(const float* __restrict__ X,
                                                     const __half* __restrict__ WhT,
                                                     const float* __restrict__ dinv,
                                                     __half* __restrict__ Y, int M) {
    int tid  = threadIdx.x;
    int wave = tid >> 6;
    int lane = tid & 63;
    int quad = lane >> 4;
    int l16  = lane & 15;
    int m0   = blockIdx.x * 64 + wave * 16;
    if (m0 >= M) return;

    f32x4 acc[8];
    #pragma unroll
    for (int t = 0; t < 8; ++t) acc[t] = (f32x4)0.0f;

    const float* xrow = X + (size_t)(m0 + l16) * D;

    #pragma unroll
    for (int ks = 0; ks < 4; ++ks) {
        int k0 = ks * 32 + quad * 8;
        float4 x0 = *(const float4*)(xrow + k0);
        float4 x1 = *(const float4*)(xrow + k0 + 4);
        half8 a;
        a[0] = (_Float16)x0.x; a[1] = (_Float16)x0.y;
        a[2] = (_Float16)x0.z; a[3] = (_Float16)x0.w;
        a[4] = (_Float16)x1.x; a[5] = (_Float16)x1.y;
        a[6] = (_Float16)x1.z; a[7] = (_Float16)x1.w;
        #pragma unroll
        for (int t = 0; t < 8; ++t) {
            half8 b = *(const half8*)(WhT + (size_t)(t * 16 + l16) * D + k0);
            acc[t] = __builtin_amdgcn_mfma_f32_16x16x32_f16(a, b, acc[t], 0, 0, 0);
        }
    }

    float4 dv = *(const float4*)(dinv + m0 + quad * 4);
    float dvs[4] = {dv.x, dv.y, dv.z, dv.w};
    #pragma unroll
    for (int t = 0; t < 8; ++t) {
        #pragma unroll
        for (int r = 0; r < 4; ++r) {
            int grow = m0 + quad * 4 + r;
            Y[(size_t)grow * D + t * 16 + l16] = __float2half(acc[t][r] * dvs[r]);
        }
    }
}

__global__ __launch_bounds__(256) void gemm_mfma_f16(const __half* __restrict__ Xh,
                                                     const __half* __restrict__ WhT,
                                                     const float* __restrict__ dinv,
                                                     __half* __restrict__ Y, int M) {
    int tid  = threadIdx.x;
    int wave = tid >> 6;
    int lane = tid & 63;
    int quad = lane >> 4;
    int l16  = lane & 15;
    int m0   = blockIdx.x * 64 + wave * 16;
    if (m0 >= M) return;

    f32x4 acc[8];
    #pragma unroll
    for (int t = 0; t < 8; ++t) acc[t] = (f32x4)0.0f;

    const __half* xrow = Xh + (size_t)(m0 + l16) * D;

    #pragma unroll
    for (int ks = 0; ks < 4; ++ks) {
        int k0 = ks * 32 + quad * 8;
        half8 a = *(const half8*)(xrow + k0);
        #pragma unroll
        for (int t = 0; t < 8; ++t) {
            half8 b = *(const half8*)(WhT + (size_t)(t * 16 + l16) * D + k0);
            acc[t] = __builtin_amdgcn_mfma_f32_16x16x32_f16(a, b, acc[t], 0, 0, 0);
        }
    }

    float4 dv = *(const float4*)(dinv + m0 + quad * 4);
    float dvs[4] = {dv.x, dv.y, dv.z, dv.w};
    #pragma unroll
    for (int t = 0; t < 8; ++t) {
        #pragma unroll
        for (int r = 0; r < 4; ++r) {
            int grow = m0 + quad * 4 + r;
            Y[(size_t)grow * D + t * 16 + l16] = __float2half(acc[t][r] * dvs[r]);
        }
    }
}

// ---------------- aggregation ----------------
// acc = ys[row] + sum_{col} ys[col]; res = b + dinv*acc
// agg_h:   h[row] = (half) relu(res)   (feeds next fp16 GEMM)
// agg_out: out[row] = (float) res      (final layer)

#define GATHER(vv, cc) __half2 vv = ((const __half2*)(ys + (size_t)(cc) * D))[lane]

template <bool FINAL>
__global__ __launch_bounds__(256) void aggregate_kernel(const __half* __restrict__ ys,
                                                        const int* __restrict__ rowptr,
                                                        const int* __restrict__ col,
                                                        const float* __restrict__ dinv,
                                                        const float* __restrict__ b,
                                                        __half* __restrict__ outh,
                                                        float* __restrict__ outf,
                                                        int N) {
    int gwave = (blockIdx.x * blockDim.x + threadIdx.x) >> 6;
    int lane  = threadIdx.x & 63;
    if (gwave >= N) return;
    int row = gwave;
    int s = rowptr[row], e = rowptr[row + 1];

    __half2 hself = ((const __half2*)(ys + (size_t)row * D))[lane];
    float2 a0 = __half22float2(hself);
    float2 a1 = make_float2(0.f, 0.f), a2 = make_float2(0.f, 0.f),
           a3 = make_float2(0.f, 0.f), a4 = make_float2(0.f, 0.f),
           a5 = make_float2(0.f, 0.f), a6 = make_float2(0.f, 0.f),
           a7 = make_float2(0.f, 0.f);

    for (int base = s; base < e; base += 64) {
        int idx = base + lane;
        int myc = (idx < e) ? col[idx] : 0;
        int nb  = min(64, e - base);
        int j = 0;
        for (; j + 16 <= nb; j += 16) {
            int c0 = __shfl(myc, j + 0),  c1 = __shfl(myc, j + 1);
            int c2 = __shfl(myc, j + 2),  c3 = __shfl(myc, j + 3);
            int c4 = __shfl(myc, j + 4),  c5 = __shfl(myc, j + 5);
            int c6 = __shfl(myc, j + 6),  c7 = __shfl(myc, j + 7);
            int c8 = __shfl(myc, j + 8),  c9 = __shfl(myc, j + 9);
            int cA = __shfl(myc, j + 10), cB = __shfl(myc, j + 11);
            int cC = __shfl(myc, j + 12), cD = __shfl(myc, j + 13);
            int cE = __shfl(myc, j + 14), cF = __shfl(myc, j + 15);
            GATHER(v0, c0); GATHER(v1, c1); GATHER(v2, c2); GATHER(v3, c3);
            GATHER(v4, c4); GATHER(v5, c5); GATHER(v6, c6); GATHER(v7, c7);
            GATHER(v8, c8); GATHER(v9, c9); GATHER(vA, cA); GATHER(vB, cB);
            GATHER(vC, cC); GATHER(vD, cD); GATHER(vE, cE); GATHER(vF, cF);
            a0.x += __low2float(v0); a0.y += __high2float(v0);
            a1.x += __low2float(v1); a1.y += __high2float(v1);
            a2.x += __low2float(v2); a2.y += __high2float(v2);
            a3.x += __low2float(v3); a3.y += __high2float(v3);
            a4.x += __low2float(v4); a4.y += __high2float(v4);
            a5.x += __low2float(v5); a5.y += __high2float(v5);
            a6.x += __low2float(v6); a6.y += __high2float(v6);
            a7.x += __low2float(v7); a7.y += __high2float(v7);
            a0.x += __low2float(v8); a0.y += __high2float(v8);
            a1.x += __low2float(v9); a1.y += __high2float(v9);
            a2.x += __low2float(vA); a2.y += __high2float(vA);
            a3.x += __low2float(vB); a3.y += __high2float(vB);
            a4.x += __low2float(vC); a4.y += __high2float(vC);
            a5.x += __low2float(vD); a5.y += __high2float(vD);
            a6.x += __low2float(vE); a6.y += __high2float(vE);
            a7.x += __low2float(vF); a7.y += __high2float(vF);
        }
        for (; j + 8 <= nb; j += 8) {
            int c0 = __shfl(myc, j + 0), c1 = __shfl(myc, j + 1);
            int c2 = __shfl(myc, j + 2), c3 = __shfl(myc, j + 3);
            int c4 = __shfl(myc, j + 4), c5 = __shfl(myc, j + 5);
            int c6 = __shfl(myc, j + 6), c7 = __shfl(myc, j + 7);
            GATHER(v0, c0); GATHER(v1, c1); GATHER(v2, c2); GATHER(v3, c3);
            GATHER(v4, c4); GATHER(v5, c5); GATHER(v6, c6); GATHER(v7, c7);
            a0.x += __low2float(v0); a0.y += __high2float(v0);
            a1.x += __low2float(v1); a1.y += __high2float(v1);
            a2.x += __low2float(v2); a2.y += __high2float(v2);
            a3.x += __low2float(v3); a3.y += __high2float(v3);
            a4.x += __low2float(v4); a4.y += __high2float(v4);
            a5.x += __low2float(v5); a5.y += __high2float(v5);
            a6.x += __low2float(v6); a6.y += __high2float(v6);
            a7.x += __low2float(v7); a7.y += __high2float(v7);
        }
        for (; j + 4 <= nb; j += 4) {
            int c0 = __shfl(myc, j + 0), c1 = __shfl(myc, j + 1);
            int c2 = __shfl(myc, j + 2), c3 = __shfl(myc, j + 3);
            GATHER(v0, c0); GATHER(v1, c1); GATHER(v2, c2); GATHER(v3, c3);
            a0.x += __low2float(v0); a0.y += __high2float(v0);
            a1.x += __low2float(v1); a1.y += __high2float(v1);
            a2.x += __low2float(v2); a2.y += __high2float(v2);
            a3.x += __low2float(v3); a3.y += __high2float(v3);
        }
        for (; j < nb; ++j) {
            int c = __shfl(myc, j);
            GATHER(v, c);
            a0.x += __low2float(v); a0.y += __high2float(v);
        }
    }
    a0.x += a1.x + a2.x + a3.x + a4.x + a5.x + a6.x + a7.x;
    a0.y += a1.y + a2.y + a3.y + a4.y + a5.y + a6.y + a7.y;

    float dv  = dinv[row];
    float2 bb = ((const float2*)b)[lane];
    float rx = bb.x + dv * a0.x;
    float ry = bb.y + dv * a0.y;
    if (FINAL) {
        ((float2*)(outf + (size_t)row * D))[lane] = make_float2(rx, ry);
    } else {
        __half2 hv = __floats2half2_rn(fmaxf(rx, 0.f), fmaxf(ry, 0.f));
        ((__half2*)(outh + (size_t)row * D))[lane] = hv;
    }
}

// ---------------- launch ----------------

extern "C" void kernel_launch(void* const* d_in, const int* in_sizes, int n_in,
                              void* d_out, int out_size, void* d_ws, size_t ws_size,
                              hipStream_t stream) {
    const float* x   = (const float*)d_in[0];
    const int*   ei  = (const int*)d_in[1];
    const float* W1  = (const float*)d_in[2];
    const float* b1  = (const float*)d_in[3];
    const float* W2  = (const float*)d_in[4];
    const float* b2  = (const float*)d_in[5];
    const float* W3  = (const float*)d_in[6];
    const float* b3  = (const float*)d_in[7];
    float* out = (float*)d_out;

    const int N = in_sizes[0] / D;
    const int E = in_sizes[1] / 2;
    const int* src = ei;
    const int* dst = ei + E;

    char* ws = (char*)d_ws;
    size_t off = 0;
    auto alloc = [&](size_t bytes) {
        void* p = ws + off;
        off = (off + bytes + 255) & ~(size_t)255;
        return p;
    };
    __half* ys    = (__half*)alloc((size_t)N * D * sizeof(__half));
    __half* hs    = (__half*)alloc((size_t)N * D * sizeof(__half));
    int*   cnt    = (int*)alloc((size_t)N * sizeof(int));
    int*   rowptr = (int*)alloc((size_t)(N + 1) * sizeof(int));
    float* dinv   = (float*)alloc((size_t)N * sizeof(float));
    int*   rank   = (int*)alloc((size_t)E * sizeof(int));
    int*   col    = (int*)alloc((size_t)E * sizeof(int));
    __half* WhT   = (__half*)alloc((size_t)3 * D * D * sizeof(__half));
    (void)ws_size; (void)n_in; (void)out_size;

    convw_kernel<<<(3 * D * D + 255) / 256, 256, 0, stream>>>(W1, W2, W3, WhT);

    hipMemsetAsync(cnt, 0, (size_t)N * sizeof(int), stream);
    const int egrid = ((E + 7) / 8 + 255) / 256;
    count_rank_kernel<<<egrid, 256, 0, stream>>>(dst, cnt, rank, E);
    scan_kernel<<<1, 1024, 0, stream>>>(cnt, rowptr, dinv, N);
    fill_kernel<<<egrid, 256, 0, stream>>>(src, dst, rank, rowptr, col, E);

    const int gemm_grid = (N + 63) / 64;
    const int agg_grid  = (N * 64 + 255) / 256;

    gemm_mfma_f32<<<gemm_grid, 256, 0, stream>>>(x, WhT, dinv, ys, N);
    aggregate_kernel<false><<<agg_grid, 256, 0, stream>>>(ys, rowptr, col, dinv, b1, hs, nullptr, N);
    gemm_mfma_f16<<<gemm_grid, 256, 0, stream>>>(hs, WhT + 16384, dinv, ys, N);
    aggregate_kernel<false><<<agg_grid, 256, 0, stream>>>(ys, rowptr, col, dinv, b2, hs, nullptr, N);
    gemm_mfma_f16<<<gemm_grid, 256, 0, stream>>>(hs, WhT + 32768, dinv, ys, N);
    aggregate_kernel<true><<<agg_grid, 256, 0, stream>>>(ys, rowptr, col, dinv, b3, nullptr, out, N);
}